// Round 13
// baseline (630.790 us; speedup 1.0000x reference)
//
#include <hip/hip_runtime.h>
#include <stdint.h>

#define BATCH 8
#define NPTS 2048
#define MPTS 2048
#define ITERS 50
#define THR2 0.25f
#define CHUNKS 32          // blocks per batch
#define SRC_PER_BLOCK 64   // NPTS / CHUNKS
#define PTS 8              // src points per thread
#define NTHREADS 1024
#define NWAVES 16
#define SLICE_LEN 16       // MPTS / (NTHREADS/PTS)

__global__ __launch_bounds__(NTHREADS)
void icp_kernel(const float* __restrict__ src,
                const float* __restrict__ tgt,
                float* __restrict__ out,
                float* __restrict__ ws)
{
    const int tid   = threadIdx.x;
    const int blk   = blockIdx.x;
    // XCD-clustered mapping (verified r12: FETCH 7.8->1.9 MB, bitwise-identical output)
    const int b     = blk & 7;       // batch
    const int chunk = blk >> 3;      // src chunk within batch, 0..31
    const int g     = tid & 7;       // src group (8 pts each)
    const int s     = tid >> 3;      // target slice 0..127
    const int lane  = tid & 63;
    const int wv    = tid >> 6;      // wave 0..15

    __shared__ float4 tgt4[MPTS];                  // (-2tx,-2ty,-2tz, |t|^2)
    __shared__ float  red[64][65];                 // slice-pair packed mins (padded rows)
    __shared__ float  srcP[SRC_PER_BLOCK][3];
    __shared__ float  gsum[CHUNKS][17];            // gathered slot values (padded)
    __shared__ float4 bcastT4[3];

    // ---- stage targets into LDS (once) ----
    const float* tb = tgt + (size_t)b * MPTS * 3;
    for (int m = tid; m < MPTS; m += NTHREADS) {
        float tx = tb[m*3+0], ty = tb[m*3+1], tz = tb[m*3+2];
        tgt4[m] = make_float4(-2.f*tx, -2.f*ty, -2.f*tz, tx*tx + ty*ty + tz*tz);
    }
    // ---- stage this block's source points ----
    const float* sb = src + (size_t)b * NPTS * 3 + (size_t)chunk * SRC_PER_BLOCK * 3;
    if (tid < SRC_PER_BLOCK) {
        srcP[tid][0] = sb[tid*3+0];
        srcP[tid][1] = sb[tid*3+1];
        srcP[tid][2] = sb[tid*3+2];
    }
    float px[PTS], py[PTS], pz[PTS];
#pragma unroll
    for (int r = 0; r < PTS; ++r) {
        int i = g*PTS + r;
        px[r] = sb[i*3+0]; py[r] = sb[i*3+1]; pz[r] = sb[i*3+2];
    }
    __syncthreads();

    // current transform (uniform, bitwise identical everywhere)
    float r00=1.f,r01=0.f,r02=0.f, r10=0.f,r11=1.f,r12=0.f, r20=0.f,r21=0.f,r22=1.f;
    float t0=0.f,t1=0.f,t2=0.f;

    // ws layout: slot64 [2][BATCH][CHUNKS][16] packed (ver<<32 | f32bits), 64 KB
    unsigned long long* slot64 = (unsigned long long*)ws;

    for (int it = 0; it < ITERS; ++it) {
        // ---- transform my 8 points ----
        float sx[PTS], sy[PTS], sz[PTS];
#pragma unroll
        for (int r = 0; r < PTS; ++r) {
            sx[r] = r00*px[r] + r01*py[r] + r02*pz[r] + t0;
            sy[r] = r10*px[r] + r11*py[r] + r12*pz[r] + t1;
            sz[r] = r20*px[r] + r21*py[r] + r22*pz[r] + t2;
        }
        float best[PTS];
#pragma unroll
        for (int r = 0; r < PTS; ++r) best[r] = __int_as_float(0x7F800000);

        const int base = s * SLICE_LEN;
        // rotated read order: 8 distinct slice rows per wave -> conflict-free broadcast
#pragma unroll 8
        for (int i = 0; i < SLICE_LEN; ++i) {
            int jo = (i + s) & (SLICE_LEN - 1);
            int jj = base + jo;
            float4 q = tgt4[jj];
#pragma unroll
            for (int r = 0; r < PTS; ++r) {
                float d = fmaf(sx[r], q.x, fmaf(sy[r], q.y, fmaf(sz[r], q.z, q.w)));
                unsigned int pd = (__float_as_uint(d) & 0xFFFFF800u) | (unsigned int)jj;
                best[r] = fminf(best[r], __uint_as_float(pd));
            }
        }
        // ---- ONE shuffle level (slice pairs), then direct LDS rows ----
        // (packed min is a total order -> any combine tree is bitwise identical)
#pragma unroll
        for (int r = 0; r < PTS; ++r) {
            float v = best[r];
            best[r] = fminf(v, __shfl_xor(v, 8, 64));   // combine s with s^1
        }
        if ((s & 1) == 0) {
            int row = s >> 1;                            // 0..63
#pragma unroll
            for (int r = 0; r < PTS; ++r) red[row][g*PTS + r] = best[r];
        }
        __syncthreads();

        if (tid < 64) {
            // final min across the 64 rows (pipelined conflict-free column reads)
            float m = red[0][tid];
#pragma unroll 8
            for (int row = 1; row < 64; ++row) m = fminf(m, red[row][tid]);
            unsigned int mb = __float_as_uint(m);
            int   bi   = (int)(mb & 0x7FFu);
            float dmin = __uint_as_float(mb & 0xFFFFF800u);

            float ppx = srcP[tid][0], ppy = srcP[tid][1], ppz = srcP[tid][2];
            float qx = r00*ppx + r01*ppy + r02*ppz + t0;
            float qy = r10*ppx + r11*ppy + r12*ppz + t1;
            float qz = r20*ppx + r21*ppy + r22*ppz + t2;
            float s2 = qx*qx + qy*qy + qz*qz;
            float w = (dmin + s2 < THR2) ? 1.f : 0.f;
            float4 nnq = tgt4[bi];
            float nx = -0.5f*nnq.x, ny = -0.5f*nnq.y, nz = -0.5f*nnq.z;

            float v[16];
            v[0]=w;      v[1]=w*qx;    v[2]=w*qy;    v[3]=w*qz;
            v[4]=w*nx;   v[5]=w*ny;    v[6]=w*nz;
            v[7]=w*qx*nx;  v[8]=w*qx*ny;  v[9]=w*qx*nz;
            v[10]=w*qy*nx; v[11]=w*qy*ny; v[12]=w*qy*nz;
            v[13]=w*qz*nx; v[14]=w*qz*ny; v[15]=w*qz*nz;
#pragma unroll
            for (int j = 0; j < 16; ++j) {
                float a = v[j];
#pragma unroll
                for (int off = 1; off < 64; off <<= 1) a += __shfl_xor(a, off, 64);
                v[j] = a;
            }
            const unsigned int want = (unsigned int)(it + 1);
            const size_t base64 = ((size_t)(it & 1) * BATCH + b) * (CHUNKS * 16);

            // ---- versioned-value publish: 16 packed 8B atomics, no drain, no stamp ----
            {
                float myv = 0.f;
#pragma unroll
                for (int j = 0; j < 16; ++j) if ((lane & 15) == j) myv = v[j];
                if (lane < 16) {
                    unsigned long long p = ((unsigned long long)want << 32)
                                         | (unsigned long long)__float_as_uint(myv);
                    __hip_atomic_store(&slot64[base64 + (size_t)chunk * 16 + lane], p,
                                       __ATOMIC_RELAXED, __HIP_MEMORY_SCOPE_AGENT);
                }
            }
            // ---- fused poll+gather: 8x 64-lane 8B loads cover all 512 (slot,comp) pairs ----
            {
                unsigned long long got[8];
                bool ok;
                do {
#pragma unroll
                    for (int k = 0; k < 8; ++k)
                        got[k] = __hip_atomic_load(&slot64[base64 + (size_t)k * 64 + lane],
                                                   __ATOMIC_RELAXED, __HIP_MEMORY_SCOPE_AGENT);
                    unsigned int vo = 1u;
#pragma unroll
                    for (int k = 0; k < 8; ++k)
                        vo &= (unsigned int)((unsigned int)(got[k] >> 32) == want);
                    ok = __all(vo != 0u);
                } while (!ok);
                asm volatile("" ::: "memory");
                // scatter values to LDS: pair idx = k*64+lane -> slot = k*4 + (lane>>4), comp = lane&15
#pragma unroll
                for (int k = 0; k < 8; ++k)
                    gsum[k*4 + (lane >> 4)][lane & 15] = __uint_as_float((unsigned int)got[k]);
            }
            // ---- sum the 32 chunk-partials in fixed slot order (bitwise round-10 order) ----
            float S_own = 0.f;
            if (tid < 16) {
#pragma unroll
                for (int c = 0; c < CHUNKS; ++c) S_own += gsum[c][tid];
            }
            float S[16];
#pragma unroll
            for (int j = 0; j < 16; ++j) S[j] = __shfl(S_own, j, 64);

            // ---- Kabsch step (wave0 only, uniform; IEEE div/sqrt — bitwise round-10) ----
            float wsum = fmaxf(S[0], 1e-6f);
            float inv  = 1.f / wsum;
            float ax=S[1], ay=S[2], az=S[3], bx=S[4], by=S[5], bz=S[6];
            float H00=S[7] -ax*bx*inv, H01=S[8] -ax*by*inv, H02=S[9] -ax*bz*inv;
            float H10=S[10]-ay*bx*inv, H11=S[11]-ay*by*inv, H12=S[12]-ay*bz*inv;
            float H20=S[13]-az*bx*inv, H21=S[14]-az*by*inv, H22=S[15]-az*bz*inv;

            float a00 = H00*H00 + H10*H10 + H20*H20;
            float a01 = H00*H01 + H10*H11 + H20*H21;
            float a02 = H00*H02 + H10*H12 + H20*H22;
            float a11 = H01*H01 + H11*H11 + H21*H21;
            float a12 = H01*H02 + H11*H12 + H21*H22;
            float a22 = H02*H02 + H12*H12 + H22*H22;

            float v00=1.f,v01=0.f,v02=0.f, v10=0.f,v11=1.f,v12=0.f, v20=0.f,v21=0.f,v22=1.f;

            auto rot = [](float &app, float &aqq, float &apq,
                          float &arp, float &arq,
                          float &vp0, float &vq0, float &vp1, float &vq1, float &vp2, float &vq2) {
                float q = apq;
                if (fabsf(q) > 1e-20f) {
                    float tau = (aqq - app) / (2.f * q);
                    float tt  = (tau >= 0.f ? 1.f : -1.f) / (fabsf(tau) + sqrtf(1.f + tau*tau));
                    float c   = 1.f / sqrtf(1.f + tt*tt);
                    float sn  = tt * c;
                    app -= tt * q;
                    aqq += tt * q;
                    apq = 0.f;
                    float x = arp, y = arq;
                    arp = c*x - sn*y;  arq = sn*x + c*y;
                    float u, w2;
                    u = vp0; w2 = vq0; vp0 = c*u - sn*w2; vq0 = sn*u + c*w2;
                    u = vp1; w2 = vq1; vp1 = c*u - sn*w2; vq1 = sn*u + c*w2;
                    u = vp2; w2 = vq2; vp2 = c*u - sn*w2; vq2 = sn*u + c*w2;
                }
            };
#pragma unroll
            for (int sw = 0; sw < 5; ++sw) {
                rot(a00, a11, a01, a02, a12, v00, v01, v10, v11, v20, v21);
                rot(a00, a22, a02, a01, a12, v00, v02, v10, v12, v20, v22);
                rot(a11, a22, a12, a01, a02, v01, v02, v11, v12, v21, v22);
            }
            {
                float tmp;
                if (a00 < a11) { tmp=a00;a00=a11;a11=tmp; tmp=v00;v00=v01;v01=tmp; tmp=v10;v10=v11;v11=tmp; tmp=v20;v20=v21;v21=tmp; }
                if (a00 < a22) { tmp=a00;a00=a22;a22=tmp; tmp=v00;v00=v02;v02=tmp; tmp=v10;v10=v12;v12=tmp; tmp=v20;v20=v22;v22=tmp; }
                if (a11 < a22) { tmp=a11;a11=a22;a22=tmp; tmp=v01;v01=v02;v02=tmp; tmp=v11;v11=v12;v12=tmp; tmp=v21;v21=v22;v22=tmp; }
            }

            float Rd00=1.f,Rd01=0.f,Rd02=0.f, Rd10=0.f,Rd11=1.f,Rd12=0.f, Rd20=0.f,Rd21=0.f,Rd22=1.f;
            {
                float u0x = H00*v00 + H01*v10 + H02*v20;
                float u0y = H10*v00 + H11*v10 + H12*v20;
                float u0z = H20*v00 + H21*v10 + H22*v20;
                float n0 = sqrtf(u0x*u0x + u0y*u0y + u0z*u0z);
                if (n0 > 1e-20f) {
                    float in0 = 1.f/n0; u0x*=in0; u0y*=in0; u0z*=in0;
                    float u1x = H00*v01 + H01*v11 + H02*v21;
                    float u1y = H10*v01 + H11*v11 + H12*v21;
                    float u1z = H20*v01 + H11*v11 + H22*v21;
                    // (exact round-12 expression retained below)
                    u1x = H00*v01 + H01*v11 + H02*v21;
                    u1y = H10*v01 + H11*v11 + H12*v21;
                    u1z = H20*v01 + H21*v11 + H22*v21;
                    float d01 = u0x*u1x + u0y*u1y + u0z*u1z;
                    u1x -= d01*u0x; u1y -= d01*u0y; u1z -= d01*u0z;
                    float n1 = sqrtf(u1x*u1x + u1y*u1y + u1z*u1z);
                    if (!(n1 > 1e-20f)) {
                        float fx = fabsf(u0x), fy = fabsf(u0y), fz = fabsf(u0z);
                        float ex=0.f, ey=0.f, ez=0.f;
                        if (fx <= fy && fx <= fz) ex = 1.f; else if (fy <= fz) ey = 1.f; else ez = 1.f;
                        u1x = u0y*ez - u0z*ey; u1y = u0z*ex - u0x*ez; u1z = u0x*ey - u0y*ex;
                        n1 = sqrtf(u1x*u1x + u1y*u1y + u1z*u1z);
                    }
                    float in1 = 1.f/n1; u1x*=in1; u1y*=in1; u1z*=in1;
                    float u2x = u0y*u1z - u0z*u1y;
                    float u2y = u0z*u1x - u0x*u1z;
                    float u2z = u0x*u1y - u0y*u1x;
                    float detV = v00*(v11*v22 - v12*v21) - v01*(v10*v22 - v12*v20) + v02*(v10*v21 - v11*v20);
                    float dsg = (detV >= 0.f) ? 1.f : -1.f;
                    Rd00 = v00*u0x + v01*u1x + dsg*v02*u2x;
                    Rd01 = v00*u0y + v01*u1y + dsg*v02*u2y;
                    Rd02 = v00*u0z + v01*u1z + dsg*v02*u2z;
                    Rd10 = v10*u0x + v11*u1x + dsg*v12*u2x;
                    Rd11 = v10*u0y + v11*u1y + dsg*v12*u2y;
                    Rd12 = v10*u0z + v11*u1z + dsg*v12*u2z;
                    Rd20 = v20*u0x + v21*u1x + dsg*v22*u2x;
                    Rd21 = v20*u0y + v21*u1y + dsg*v22*u2y;
                    Rd22 = v20*u0z + v21*u1z + dsg*v22*u2z;
                }
            }
            float csx = ax*inv, csy = ay*inv, csz = az*inv;
            float ctx = bx*inv, cty = by*inv, ctz = bz*inv;
            float tdx = ctx - (Rd00*csx + Rd01*csy + Rd02*csz);
            float tdy = cty - (Rd10*csx + Rd11*csy + Rd12*csz);
            float tdz = ctz - (Rd20*csx + Rd21*csy + Rd22*csz);

            // T_new = delta * T_old
            float nr00 = Rd00*r00 + Rd01*r10 + Rd02*r20;
            float nr01 = Rd00*r01 + Rd01*r11 + Rd02*r21;
            float nr02 = Rd00*r02 + Rd01*r12 + Rd02*r22;
            float nr10 = Rd10*r00 + Rd11*r10 + Rd12*r20;
            float nr11 = Rd10*r01 + Rd11*r11 + Rd12*r21;
            float nr12 = Rd10*r02 + Rd11*r12 + Rd12*r22;
            float nr20 = Rd20*r00 + Rd21*r10 + Rd22*r20;
            float nr21 = Rd20*r01 + Rd21*r11 + Rd22*r21;
            float nr22 = Rd20*r02 + Rd21*r12 + Rd22*r22;
            float nt0 = Rd00*t0 + Rd01*t1 + Rd02*t2 + tdx;
            float nt1 = Rd10*t0 + Rd11*t1 + Rd12*t2 + tdy;
            float nt2 = Rd20*t0 + Rd21*t1 + Rd22*t2 + tdz;

            if (tid == 0) {
                bcastT4[0] = make_float4(nr00, nr01, nr02, nt0);
                bcastT4[1] = make_float4(nr10, nr11, nr12, nt1);
                bcastT4[2] = make_float4(nr20, nr21, nr22, nt2);
            }
        }
        __syncthreads();
        {
            float4 tA = bcastT4[0], tB = bcastT4[1], tC = bcastT4[2];
            r00=tA.x; r01=tA.y; r02=tA.z; t0=tA.w;
            r10=tB.x; r11=tB.y; r12=tB.z; t1=tB.w;
            r20=tC.x; r21=tC.y; r22=tC.z; t2=tC.w;
        }
    }

    if (chunk == 0 && tid == 0) {
        float* o = out + (size_t)b * 16;
        o[0]=r00;  o[1]=r01;  o[2]=r02;  o[3]=t0;
        o[4]=r10;  o[5]=r11;  o[6]=r12;  o[7]=t1;
        o[8]=r20;  o[9]=r21;  o[10]=r22; o[11]=t2;
        o[12]=0.f; o[13]=0.f; o[14]=0.f; o[15]=1.f;
    }
}

extern "C" void kernel_launch(void* const* d_in, const int* in_sizes, int n_in,
                              void* d_out, int out_size, void* d_ws, size_t ws_size,
                              hipStream_t stream) {
    const float* src = (const float*)d_in[0];
    const float* tgt = (const float*)d_in[1];
    float* out = (float*)d_out;
    float* ws  = (float*)d_ws;

    // zero the versioned slot region (64 KB) every launch — kills cross-replay aliasing
    hipMemsetAsync(d_ws, 0, 2 * BATCH * CHUNKS * 16 * sizeof(unsigned long long), stream);

    void* args[] = { (void*)&src, (void*)&tgt, (void*)&out, (void*)&ws };
    hipLaunchCooperativeKernel((const void*)icp_kernel,
                               dim3(BATCH * CHUNKS), dim3(NTHREADS),
                               args, 0, stream);
}

// Round 14
// 592.372 us; speedup vs baseline: 1.0649x; 1.0649x over previous
//
#include <hip/hip_runtime.h>
#include <stdint.h>

#define BATCH 8
#define NPTS 2048
#define MPTS 2048
#define ITERS 50
#define THR2 0.25f
#define CHUNKS 32          // blocks per batch
#define SRC_PER_BLOCK 64   // NPTS / CHUNKS
#define PTS 8              // src points per thread
#define NTHREADS 1024
#define NWAVES 16
#define SLICE_LEN 16       // MPTS / (NTHREADS/PTS)

__global__ __launch_bounds__(NTHREADS)
void icp_kernel(const float* __restrict__ src,
                const float* __restrict__ tgt,
                float* __restrict__ out,
                float* __restrict__ ws)
{
    const int tid   = threadIdx.x;
    const int blk   = blockIdx.x;
    // XCD-clustered mapping (verified r12: FETCH 7.8->1.9 MB, bitwise-identical output)
    const int b     = blk & 7;       // batch
    const int chunk = blk >> 3;      // src chunk within batch, 0..31
    const int g     = tid & 7;       // src group (8 pts each)
    const int s     = tid >> 3;      // target slice 0..127
    const int lane  = tid & 63;
    const int wv    = tid >> 6;      // wave 0..15

    __shared__ float4 tgt4[MPTS];                  // (-2tx,-2ty,-2tz, |t|^2)
    __shared__ float  red[NWAVES][65];             // per-wave packed mins (padded row)
    __shared__ float  srcP[SRC_PER_BLOCK][3];
    __shared__ float  gsum[CHUNKS][17];            // gathered slot values (padded)
    __shared__ float4 bcastT4[3];

    // ---- stage targets into LDS (once) ----
    const float* tb = tgt + (size_t)b * MPTS * 3;
    for (int m = tid; m < MPTS; m += NTHREADS) {
        float tx = tb[m*3+0], ty = tb[m*3+1], tz = tb[m*3+2];
        tgt4[m] = make_float4(-2.f*tx, -2.f*ty, -2.f*tz, tx*tx + ty*ty + tz*tz);
    }
    // ---- stage this block's source points ----
    const float* sb = src + (size_t)b * NPTS * 3 + (size_t)chunk * SRC_PER_BLOCK * 3;
    if (tid < SRC_PER_BLOCK) {
        srcP[tid][0] = sb[tid*3+0];
        srcP[tid][1] = sb[tid*3+1];
        srcP[tid][2] = sb[tid*3+2];
    }
    float px[PTS], py[PTS], pz[PTS];
#pragma unroll
    for (int r = 0; r < PTS; ++r) {
        int i = g*PTS + r;
        px[r] = sb[i*3+0]; py[r] = sb[i*3+1]; pz[r] = sb[i*3+2];
    }
    __syncthreads();

    // current transform (uniform, bitwise identical everywhere)
    float r00=1.f,r01=0.f,r02=0.f, r10=0.f,r11=1.f,r12=0.f, r20=0.f,r21=0.f,r22=1.f;
    float t0=0.f,t1=0.f,t2=0.f;

    // ws layout: slot64 [2][BATCH][CHUNKS][16] packed (ver<<32 | f32bits), 64 KB
    unsigned long long* slot64 = (unsigned long long*)ws;

    for (int it = 0; it < ITERS; ++it) {
        // ---- transform my 8 points ----
        float sx[PTS], sy[PTS], sz[PTS];
#pragma unroll
        for (int r = 0; r < PTS; ++r) {
            sx[r] = r00*px[r] + r01*py[r] + r02*pz[r] + t0;
            sy[r] = r10*px[r] + r11*py[r] + r12*pz[r] + t1;
            sz[r] = r20*px[r] + r21*py[r] + r22*pz[r] + t2;
        }
        float best[PTS];
#pragma unroll
        for (int r = 0; r < PTS; ++r) best[r] = __int_as_float(0x7F800000);

        const int base = s * SLICE_LEN;
        // rotated read order: 8 distinct slice rows per wave -> conflict-free broadcast
#pragma unroll 8
        for (int i = 0; i < SLICE_LEN; ++i) {
            int jo = (i + s) & (SLICE_LEN - 1);
            int jj = base + jo;
            float4 q = tgt4[jj];
#pragma unroll
            for (int r = 0; r < PTS; ++r) {
                float d = fmaf(sx[r], q.x, fmaf(sy[r], q.y, fmaf(sz[r], q.z, q.w)));
                unsigned int pd = (__float_as_uint(d) & 0xFFFFF800u) | (unsigned int)jj;
                best[r] = fminf(best[r], __uint_as_float(pd));
            }
        }
        // ---- combine the 8 slices within each wave (exact min, in-register; r12 path) ----
#pragma unroll
        for (int r = 0; r < PTS; ++r) {
            float v = best[r];
            v = fminf(v, __shfl_xor(v, 8, 64));
            v = fminf(v, __shfl_xor(v, 16, 64));
            v = fminf(v, __shfl_xor(v, 32, 64));
            best[r] = v;
        }
        if (lane < 8) {       // lanes with s_local==0: g == lane
#pragma unroll
            for (int r = 0; r < PTS; ++r) red[wv][lane*PTS + r] = best[r];
        }
        __syncthreads();

        const unsigned int want = (unsigned int)(it + 1);
        const size_t base64 = ((size_t)(it & 1) * BATCH + b) * (CHUNKS * 16);

        // ---- ALL 16 waves: redundant column-min + weights; wave wv butterflies
        //      component wv only (6 bpermutes) and publishes it from lane 0.
        //      Same butterfly tree per component as r12 -> S bitwise identical. ----
        {
            float m = red[0][lane];
#pragma unroll
            for (int ww = 1; ww < NWAVES; ++ww) m = fminf(m, red[ww][lane]);
            unsigned int mb = __float_as_uint(m);
            int   bi   = (int)(mb & 0x7FFu);
            float dmin = __uint_as_float(mb & 0xFFFFF800u);

            float ppx = srcP[lane][0], ppy = srcP[lane][1], ppz = srcP[lane][2];
            float qx = r00*ppx + r01*ppy + r02*ppz + t0;
            float qy = r10*ppx + r11*ppy + r12*ppz + t1;
            float qz = r20*ppx + r21*ppy + r22*ppz + t2;
            float s2 = qx*qx + qy*qy + qz*qz;
            float w = (dmin + s2 < THR2) ? 1.f : 0.f;
            float4 nnq = tgt4[bi];
            float nx = -0.5f*nnq.x, ny = -0.5f*nnq.y, nz = -0.5f*nnq.z;

            float wqx = w*qx, wqy = w*qy, wqz = w*qz;
            float a;                       // component wv (wave-uniform branch, no arrays)
            if      (wv == 0)  a = w;
            else if (wv == 1)  a = wqx;
            else if (wv == 2)  a = wqy;
            else if (wv == 3)  a = wqz;
            else if (wv == 4)  a = w*nx;
            else if (wv == 5)  a = w*ny;
            else if (wv == 6)  a = w*nz;
            else if (wv == 7)  a = wqx*nx;
            else if (wv == 8)  a = wqx*ny;
            else if (wv == 9)  a = wqx*nz;
            else if (wv == 10) a = wqy*nx;
            else if (wv == 11) a = wqy*ny;
            else if (wv == 12) a = wqy*nz;
            else if (wv == 13) a = wqz*nx;
            else if (wv == 14) a = wqz*ny;
            else               a = wqz*nz;
#pragma unroll
            for (int off = 1; off < 64; off <<= 1) a += __shfl_xor(a, off, 64);

            if (lane == 0) {
                unsigned long long p = ((unsigned long long)want << 32)
                                     | (unsigned long long)__float_as_uint(a);
                __hip_atomic_store(&slot64[base64 + (size_t)chunk * 16 + wv], p,
                                   __ATOMIC_RELAXED, __HIP_MEMORY_SCOPE_AGENT);
            }
        }

        // ---- wave 0: fused poll+gather, sum, Kabsch (identical to r12) ----
        if (tid < 64) {
            {
                unsigned long long got[8];
                bool ok;
                do {
#pragma unroll
                    for (int k = 0; k < 8; ++k)
                        got[k] = __hip_atomic_load(&slot64[base64 + (size_t)k * 64 + lane],
                                                   __ATOMIC_RELAXED, __HIP_MEMORY_SCOPE_AGENT);
                    unsigned int vo = 1u;
#pragma unroll
                    for (int k = 0; k < 8; ++k)
                        vo &= (unsigned int)((unsigned int)(got[k] >> 32) == want);
                    ok = __all(vo != 0u);
                } while (!ok);
                asm volatile("" ::: "memory");
                // pair idx = k*64+lane -> slot = k*4 + (lane>>4), comp = lane&15
#pragma unroll
                for (int k = 0; k < 8; ++k)
                    gsum[k*4 + (lane >> 4)][lane & 15] = __uint_as_float((unsigned int)got[k]);
            }
            float S_own = 0.f;
            if (tid < 16) {
#pragma unroll
                for (int c = 0; c < CHUNKS; ++c) S_own += gsum[c][tid];
            }
            float S[16];
#pragma unroll
            for (int j = 0; j < 16; ++j) S[j] = __shfl(S_own, j, 64);

            // ---- Kabsch step (wave0 only, uniform; IEEE div/sqrt — bitwise round-12) ----
            float wsum = fmaxf(S[0], 1e-6f);
            float inv  = 1.f / wsum;
            float ax=S[1], ay=S[2], az=S[3], bx=S[4], by=S[5], bz=S[6];
            float H00=S[7] -ax*bx*inv, H01=S[8] -ax*by*inv, H02=S[9] -ax*bz*inv;
            float H10=S[10]-ay*bx*inv, H11=S[11]-ay*by*inv, H12=S[12]-ay*bz*inv;
            float H20=S[13]-az*bx*inv, H21=S[14]-az*by*inv, H22=S[15]-az*bz*inv;

            float a00 = H00*H00 + H10*H10 + H20*H20;
            float a01 = H00*H01 + H10*H11 + H20*H21;
            float a02 = H00*H02 + H10*H12 + H20*H22;
            float a11 = H01*H01 + H11*H11 + H21*H21;
            float a12 = H01*H02 + H11*H12 + H21*H22;
            float a22 = H02*H02 + H12*H12 + H22*H22;

            float v00=1.f,v01=0.f,v02=0.f, v10=0.f,v11=1.f,v12=0.f, v20=0.f,v21=0.f,v22=1.f;

            auto rot = [](float &app, float &aqq, float &apq,
                          float &arp, float &arq,
                          float &vp0, float &vq0, float &vp1, float &vq1, float &vp2, float &vq2) {
                float q = apq;
                if (fabsf(q) > 1e-20f) {
                    float tau = (aqq - app) / (2.f * q);
                    float tt  = (tau >= 0.f ? 1.f : -1.f) / (fabsf(tau) + sqrtf(1.f + tau*tau));
                    float c   = 1.f / sqrtf(1.f + tt*tt);
                    float sn  = tt * c;
                    app -= tt * q;
                    aqq += tt * q;
                    apq = 0.f;
                    float x = arp, y = arq;
                    arp = c*x - sn*y;  arq = sn*x + c*y;
                    float u, w2;
                    u = vp0; w2 = vq0; vp0 = c*u - sn*w2; vq0 = sn*u + c*w2;
                    u = vp1; w2 = vq1; vp1 = c*u - sn*w2; vq1 = sn*u + c*w2;
                    u = vp2; w2 = vq2; vp2 = c*u - sn*w2; vq2 = sn*u + c*w2;
                }
            };
#pragma unroll
            for (int sw = 0; sw < 5; ++sw) {
                rot(a00, a11, a01, a02, a12, v00, v01, v10, v11, v20, v21);
                rot(a00, a22, a02, a01, a12, v00, v02, v10, v12, v20, v22);
                rot(a11, a22, a12, a01, a02, v01, v02, v11, v12, v21, v22);
            }
            {
                float tmp;
                if (a00 < a11) { tmp=a00;a00=a11;a11=tmp; tmp=v00;v00=v01;v01=tmp; tmp=v10;v10=v11;v11=tmp; tmp=v20;v20=v21;v21=tmp; }
                if (a00 < a22) { tmp=a00;a00=a22;a22=tmp; tmp=v00;v00=v02;v02=tmp; tmp=v10;v10=v12;v12=tmp; tmp=v20;v20=v22;v22=tmp; }
                if (a11 < a22) { tmp=a11;a11=a22;a22=tmp; tmp=v01;v01=v02;v02=tmp; tmp=v11;v11=v12;v12=tmp; tmp=v21;v21=v22;v22=tmp; }
            }

            float Rd00=1.f,Rd01=0.f,Rd02=0.f, Rd10=0.f,Rd11=1.f,Rd12=0.f, Rd20=0.f,Rd21=0.f,Rd22=1.f;
            {
                float u0x = H00*v00 + H01*v10 + H02*v20;
                float u0y = H10*v00 + H11*v10 + H12*v20;
                float u0z = H20*v00 + H21*v10 + H22*v20;
                float n0 = sqrtf(u0x*u0x + u0y*u0y + u0z*u0z);
                if (n0 > 1e-20f) {
                    float in0 = 1.f/n0; u0x*=in0; u0y*=in0; u0z*=in0;
                    float u1x = H00*v01 + H01*v11 + H02*v21;
                    float u1y = H10*v01 + H11*v11 + H12*v21;
                    float u1z = H20*v01 + H21*v11 + H22*v21;
                    float d01 = u0x*u1x + u0y*u1y + u0z*u1z;
                    u1x -= d01*u0x; u1y -= d01*u0y; u1z -= d01*u0z;
                    float n1 = sqrtf(u1x*u1x + u1y*u1y + u1z*u1z);
                    if (!(n1 > 1e-20f)) {
                        float fx = fabsf(u0x), fy = fabsf(u0y), fz = fabsf(u0z);
                        float ex=0.f, ey=0.f, ez=0.f;
                        if (fx <= fy && fx <= fz) ex = 1.f; else if (fy <= fz) ey = 1.f; else ez = 1.f;
                        u1x = u0y*ez - u0z*ey; u1y = u0z*ex - u0x*ez; u1z = u0x*ey - u0y*ex;
                        n1 = sqrtf(u1x*u1x + u1y*u1y + u1z*u1z);
                    }
                    float in1 = 1.f/n1; u1x*=in1; u1y*=in1; u1z*=in1;
                    float u2x = u0y*u1z - u0z*u1y;
                    float u2y = u0z*u1x - u0x*u1z;
                    float u2z = u0x*u1y - u0y*u1x;
                    float detV = v00*(v11*v22 - v12*v21) - v01*(v10*v22 - v12*v20) + v02*(v10*v21 - v11*v20);
                    float dsg = (detV >= 0.f) ? 1.f : -1.f;
                    Rd00 = v00*u0x + v01*u1x + dsg*v02*u2x;
                    Rd01 = v00*u0y + v01*u1y + dsg*v02*u2y;
                    Rd02 = v00*u0z + v01*u1z + dsg*v02*u2z;
                    Rd10 = v10*u0x + v11*u1x + dsg*v12*u2x;
                    Rd11 = v10*u0y + v11*u1y + dsg*v12*u2y;
                    Rd12 = v10*u0z + v11*u1z + dsg*v12*u2z;
                    Rd20 = v20*u0x + v21*u1x + dsg*v22*u2x;
                    Rd21 = v20*u0y + v21*u1y + dsg*v22*u2y;
                    Rd22 = v20*u0z + v21*u1z + dsg*v22*u2z;
                }
            }
            float csx = ax*inv, csy = ay*inv, csz = az*inv;
            float ctx = bx*inv, cty = by*inv, ctz = bz*inv;
            float tdx = ctx - (Rd00*csx + Rd01*csy + Rd02*csz);
            float tdy = cty - (Rd10*csx + Rd11*csy + Rd12*csz);
            float tdz = ctz - (Rd20*csx + Rd21*csy + Rd22*csz);

            // T_new = delta * T_old
            float nr00 = Rd00*r00 + Rd01*r10 + Rd02*r20;
            float nr01 = Rd00*r01 + Rd01*r11 + Rd02*r21;
            float nr02 = Rd00*r02 + Rd01*r12 + Rd02*r22;
            float nr10 = Rd10*r00 + Rd11*r10 + Rd12*r20;
            float nr11 = Rd10*r01 + Rd11*r11 + Rd12*r21;
            float nr12 = Rd10*r02 + Rd11*r12 + Rd12*r22;
            float nr20 = Rd20*r00 + Rd21*r10 + Rd22*r20;
            float nr21 = Rd20*r01 + Rd21*r11 + Rd22*r21;
            float nr22 = Rd20*r02 + Rd21*r12 + Rd22*r22;
            float nt0 = Rd00*t0 + Rd01*t1 + Rd02*t2 + tdx;
            float nt1 = Rd10*t0 + Rd11*t1 + Rd12*t2 + tdy;
            float nt2 = Rd20*t0 + Rd21*t1 + Rd22*t2 + tdz;

            if (tid == 0) {
                bcastT4[0] = make_float4(nr00, nr01, nr02, nt0);
                bcastT4[1] = make_float4(nr10, nr11, nr12, nt1);
                bcastT4[2] = make_float4(nr20, nr21, nr22, nt2);
            }
        }
        __syncthreads();
        {
            float4 tA = bcastT4[0], tB = bcastT4[1], tC = bcastT4[2];
            r00=tA.x; r01=tA.y; r02=tA.z; t0=tA.w;
            r10=tB.x; r11=tB.y; r12=tB.z; t1=tB.w;
            r20=tC.x; r21=tC.y; r22=tC.z; t2=tC.w;
        }
    }

    if (chunk == 0 && tid == 0) {
        float* o = out + (size_t)b * 16;
        o[0]=r00;  o[1]=r01;  o[2]=r02;  o[3]=t0;
        o[4]=r10;  o[5]=r11;  o[6]=r12;  o[7]=t1;
        o[8]=r20;  o[9]=r21;  o[10]=r22; o[11]=t2;
        o[12]=0.f; o[13]=0.f; o[14]=0.f; o[15]=1.f;
    }
}

extern "C" void kernel_launch(void* const* d_in, const int* in_sizes, int n_in,
                              void* d_out, int out_size, void* d_ws, size_t ws_size,
                              hipStream_t stream) {
    const float* src = (const float*)d_in[0];
    const float* tgt = (const float*)d_in[1];
    float* out = (float*)d_out;
    float* ws  = (float*)d_ws;

    // zero the versioned slot region (64 KB) every launch — kills cross-replay aliasing
    hipMemsetAsync(d_ws, 0, 2 * BATCH * CHUNKS * 16 * sizeof(unsigned long long), stream);

    void* args[] = { (void*)&src, (void*)&tgt, (void*)&out, (void*)&ws };
    hipLaunchCooperativeKernel((const void*)icp_kernel,
                               dim3(BATCH * CHUNKS), dim3(NTHREADS),
                               args, 0, stream);
}

// Round 15
// 507.748 us; speedup vs baseline: 1.2423x; 1.1667x over previous
//
#include <hip/hip_runtime.h>
#include <stdint.h>

#define BATCH 8
#define NPTS 2048
#define MPTS 2048
#define ITERS 50
#define THR2 0.25f
#define CHUNKS 32          // blocks per batch
#define SRC_PER_BLOCK 64   // NPTS / CHUNKS
#define PTS 8              // src points per thread
#define NTHREADS 1024
#define NWAVES 16
#define SLICE_LEN 16       // MPTS / (NTHREADS/PTS)

__global__ __launch_bounds__(NTHREADS)
void icp_kernel(const float* __restrict__ src,
                const float* __restrict__ tgt,
                float* __restrict__ out,
                float* __restrict__ ws)
{
    const int tid   = threadIdx.x;
    const int blk   = blockIdx.x;
    // XCD-clustered mapping (verified r12: FETCH 7.8->1.9 MB, bitwise-identical output)
    const int b     = blk & 7;       // batch
    const int chunk = blk >> 3;      // src chunk within batch, 0..31
    const int g     = tid & 7;       // src group (8 pts each)
    const int s     = tid >> 3;      // target slice 0..127
    const int lane  = tid & 63;
    const int wv    = tid >> 6;      // wave 0..15

    __shared__ float4 tgt4[MPTS];                  // (-2tx,-2ty,-2tz, |t|^2)
    __shared__ float  red[NWAVES][65];             // per-wave packed mins (padded row)
    __shared__ float  srcP[SRC_PER_BLOCK][3];
    __shared__ float  gsum[CHUNKS][17];            // gathered slot values (padded)
    __shared__ float4 bcastT4[3];

    // ---- stage targets into LDS (once) ----
    const float* tb = tgt + (size_t)b * MPTS * 3;
    for (int m = tid; m < MPTS; m += NTHREADS) {
        float tx = tb[m*3+0], ty = tb[m*3+1], tz = tb[m*3+2];
        tgt4[m] = make_float4(-2.f*tx, -2.f*ty, -2.f*tz, tx*tx + ty*ty + tz*tz);
    }
    // ---- stage this block's source points ----
    const float* sb = src + (size_t)b * NPTS * 3 + (size_t)chunk * SRC_PER_BLOCK * 3;
    if (tid < SRC_PER_BLOCK) {
        srcP[tid][0] = sb[tid*3+0];
        srcP[tid][1] = sb[tid*3+1];
        srcP[tid][2] = sb[tid*3+2];
    }
    float px[PTS], py[PTS], pz[PTS];
#pragma unroll
    for (int r = 0; r < PTS; ++r) {
        int i = g*PTS + r;
        px[r] = sb[i*3+0]; py[r] = sb[i*3+1]; pz[r] = sb[i*3+2];
    }
    __syncthreads();

    // current transform (uniform, bitwise identical everywhere)
    float r00=1.f,r01=0.f,r02=0.f, r10=0.f,r11=1.f,r12=0.f, r20=0.f,r21=0.f,r22=1.f;
    float t0=0.f,t1=0.f,t2=0.f;

    // ws layout: slot64 [2][BATCH][CHUNKS][16] packed (ver<<32 | f32bits), 64 KB
    unsigned long long* slot64 = (unsigned long long*)ws;

    for (int it = 0; it < ITERS; ++it) {
        // ---- transform my 8 points ----
        float sx[PTS], sy[PTS], sz[PTS];
#pragma unroll
        for (int r = 0; r < PTS; ++r) {
            sx[r] = r00*px[r] + r01*py[r] + r02*pz[r] + t0;
            sy[r] = r10*px[r] + r11*py[r] + r12*pz[r] + t1;
            sz[r] = r20*px[r] + r21*py[r] + r22*pz[r] + t2;
        }
        float best[PTS];
#pragma unroll
        for (int r = 0; r < PTS; ++r) best[r] = __int_as_float(0x7F800000);

        const int base = s * SLICE_LEN;
        // rotated read order: 8 distinct slice rows per wave -> conflict-free broadcast
#pragma unroll 8
        for (int i = 0; i < SLICE_LEN; ++i) {
            int jo = (i + s) & (SLICE_LEN - 1);
            int jj = base + jo;
            float4 q = tgt4[jj];
#pragma unroll
            for (int r = 0; r < PTS; ++r) {
                float d = fmaf(sx[r], q.x, fmaf(sy[r], q.y, fmaf(sz[r], q.z, q.w)));
                unsigned int pd = (__float_as_uint(d) & 0xFFFFF800u) | (unsigned int)jj;
                best[r] = fminf(best[r], __uint_as_float(pd));
            }
        }
        // ---- combine the 8 slices within each wave (exact min, in-register) ----
#pragma unroll
        for (int r = 0; r < PTS; ++r) {
            float v = best[r];
            v = fminf(v, __shfl_xor(v, 8, 64));
            v = fminf(v, __shfl_xor(v, 16, 64));
            v = fminf(v, __shfl_xor(v, 32, 64));
            best[r] = v;
        }
        if (lane < 8) {       // lanes with s_local==0: g == lane
#pragma unroll
            for (int r = 0; r < PTS; ++r) red[wv][lane*PTS + r] = best[r];
        }
        __syncthreads();

        if (tid < 64) {
            // final min across the 16 waves
            float m = red[0][tid];
#pragma unroll
            for (int ww = 1; ww < NWAVES; ++ww) m = fminf(m, red[ww][tid]);
            unsigned int mb = __float_as_uint(m);
            int   bi   = (int)(mb & 0x7FFu);
            float dmin = __uint_as_float(mb & 0xFFFFF800u);

            float ppx = srcP[tid][0], ppy = srcP[tid][1], ppz = srcP[tid][2];
            float qx = r00*ppx + r01*ppy + r02*ppz + t0;
            float qy = r10*ppx + r11*ppy + r12*ppz + t1;
            float qz = r20*ppx + r21*ppy + r22*ppz + t2;
            float s2 = qx*qx + qy*qy + qz*qz;
            float w = (dmin + s2 < THR2) ? 1.f : 0.f;
            float4 nnq = tgt4[bi];
            float nx = -0.5f*nnq.x, ny = -0.5f*nnq.y, nz = -0.5f*nnq.z;

            float v[16];
            v[0]=w;      v[1]=w*qx;    v[2]=w*qy;    v[3]=w*qz;
            v[4]=w*nx;   v[5]=w*ny;    v[6]=w*nz;
            v[7]=w*qx*nx;  v[8]=w*qx*ny;  v[9]=w*qx*nz;
            v[10]=w*qy*nx; v[11]=w*qy*ny; v[12]=w*qy*nz;
            v[13]=w*qz*nx; v[14]=w*qz*ny; v[15]=w*qz*nz;
#pragma unroll
            for (int j = 0; j < 16; ++j) {
                float a = v[j];
#pragma unroll
                for (int off = 1; off < 64; off <<= 1) a += __shfl_xor(a, off, 64);
                v[j] = a;
            }
            const unsigned int want = (unsigned int)(it + 1);
            const size_t base64 = ((size_t)(it & 1) * BATCH + b) * (CHUNKS * 16);

            // ---- versioned-value publish: 16 packed 8B atomics, no drain, no stamp ----
            {
                float myv = 0.f;
#pragma unroll
                for (int j = 0; j < 16; ++j) if ((lane & 15) == j) myv = v[j];
                if (lane < 16) {
                    unsigned long long p = ((unsigned long long)want << 32)
                                         | (unsigned long long)__float_as_uint(myv);
                    __hip_atomic_store(&slot64[base64 + (size_t)chunk * 16 + lane], p,
                                       __ATOMIC_RELAXED, __HIP_MEMORY_SCOPE_AGENT);
                }
            }
            // ---- fused poll+gather: 8x 64-lane 8B loads cover all 512 (slot,comp) pairs ----
            {
                unsigned long long got[8];
                bool ok;
                do {
#pragma unroll
                    for (int k = 0; k < 8; ++k)
                        got[k] = __hip_atomic_load(&slot64[base64 + (size_t)k * 64 + lane],
                                                   __ATOMIC_RELAXED, __HIP_MEMORY_SCOPE_AGENT);
                    unsigned int vo = 1u;
#pragma unroll
                    for (int k = 0; k < 8; ++k)
                        vo &= (unsigned int)((unsigned int)(got[k] >> 32) == want);
                    ok = __all(vo != 0u);
                } while (!ok);
                asm volatile("" ::: "memory");
                // scatter values to LDS: pair idx = k*64+lane -> slot = k*4 + (lane>>4), comp = lane&15
#pragma unroll
                for (int k = 0; k < 8; ++k)
                    gsum[k*4 + (lane >> 4)][lane & 15] = __uint_as_float((unsigned int)got[k]);
            }
            // ---- sum the 32 chunk-partials in fixed slot order (bitwise round-10 order) ----
            float S_own = 0.f;
            if (tid < 16) {
#pragma unroll
                for (int c = 0; c < CHUNKS; ++c) S_own += gsum[c][tid];
            }
            float S[16];
#pragma unroll
            for (int j = 0; j < 16; ++j) S[j] = __shfl(S_own, j, 64);

            // ---- Kabsch step (wave0 only, uniform; IEEE div/sqrt — bitwise round-10) ----
            float wsum = fmaxf(S[0], 1e-6f);
            float inv  = 1.f / wsum;
            float ax=S[1], ay=S[2], az=S[3], bx=S[4], by=S[5], bz=S[6];
            float H00=S[7] -ax*bx*inv, H01=S[8] -ax*by*inv, H02=S[9] -ax*bz*inv;
            float H10=S[10]-ay*bx*inv, H11=S[11]-ay*by*inv, H12=S[12]-ay*bz*inv;
            float H20=S[13]-az*bx*inv, H21=S[14]-az*by*inv, H22=S[15]-az*bz*inv;

            float a00 = H00*H00 + H10*H10 + H20*H20;
            float a01 = H00*H01 + H10*H11 + H20*H21;
            float a02 = H00*H02 + H10*H12 + H20*H22;
            float a11 = H01*H01 + H11*H11 + H21*H21;
            float a12 = H01*H02 + H11*H12 + H21*H22;
            float a22 = H02*H02 + H12*H12 + H22*H22;

            float v00=1.f,v01=0.f,v02=0.f, v10=0.f,v11=1.f,v12=0.f, v20=0.f,v21=0.f,v22=1.f;

            auto rot = [](float &app, float &aqq, float &apq,
                          float &arp, float &arq,
                          float &vp0, float &vq0, float &vp1, float &vq1, float &vp2, float &vq2) {
                float q = apq;
                if (fabsf(q) > 1e-20f) {
                    float tau = (aqq - app) / (2.f * q);
                    float tt  = (tau >= 0.f ? 1.f : -1.f) / (fabsf(tau) + sqrtf(1.f + tau*tau));
                    float c   = 1.f / sqrtf(1.f + tt*tt);
                    float sn  = tt * c;
                    app -= tt * q;
                    aqq += tt * q;
                    apq = 0.f;
                    float x = arp, y = arq;
                    arp = c*x - sn*y;  arq = sn*x + c*y;
                    float u, w2;
                    u = vp0; w2 = vq0; vp0 = c*u - sn*w2; vq0 = sn*u + c*w2;
                    u = vp1; w2 = vq1; vp1 = c*u - sn*w2; vq1 = sn*u + c*w2;
                    u = vp2; w2 = vq2; vp2 = c*u - sn*w2; vq2 = sn*u + c*w2;
                }
            };
#pragma unroll
            for (int sw = 0; sw < 5; ++sw) {
                rot(a00, a11, a01, a02, a12, v00, v01, v10, v11, v20, v21);
                rot(a00, a22, a02, a01, a12, v00, v02, v10, v12, v20, v22);
                rot(a11, a22, a12, a01, a02, v01, v02, v11, v12, v21, v22);
            }
            {
                float tmp;
                if (a00 < a11) { tmp=a00;a00=a11;a11=tmp; tmp=v00;v00=v01;v01=tmp; tmp=v10;v10=v11;v11=tmp; tmp=v20;v20=v21;v21=tmp; }
                if (a00 < a22) { tmp=a00;a00=a22;a22=tmp; tmp=v00;v00=v02;v02=tmp; tmp=v10;v10=v12;v12=tmp; tmp=v20;v20=v22;v22=tmp; }
                if (a11 < a22) { tmp=a11;a11=a22;a22=tmp; tmp=v01;v01=v02;v02=tmp; tmp=v11;v11=v12;v12=tmp; tmp=v21;v21=v22;v22=tmp; }
            }

            float Rd00=1.f,Rd01=0.f,Rd02=0.f, Rd10=0.f,Rd11=1.f,Rd12=0.f, Rd20=0.f,Rd21=0.f,Rd22=1.f;
            {
                float u0x = H00*v00 + H01*v10 + H02*v20;
                float u0y = H10*v00 + H11*v10 + H12*v20;
                float u0z = H20*v00 + H21*v10 + H22*v20;
                float n0 = sqrtf(u0x*u0x + u0y*u0y + u0z*u0z);
                if (n0 > 1e-20f) {
                    float in0 = 1.f/n0; u0x*=in0; u0y*=in0; u0z*=in0;
                    float u1x = H00*v01 + H01*v11 + H02*v21;
                    float u1y = H10*v01 + H11*v11 + H12*v21;
                    float u1z = H20*v01 + H21*v11 + H22*v21;
                    float d01 = u0x*u1x + u0y*u1y + u0z*u1z;
                    u1x -= d01*u0x; u1y -= d01*u0y; u1z -= d01*u0z;
                    float n1 = sqrtf(u1x*u1x + u1y*u1y + u1z*u1z);
                    if (!(n1 > 1e-20f)) {
                        float fx = fabsf(u0x), fy = fabsf(u0y), fz = fabsf(u0z);
                        float ex=0.f, ey=0.f, ez=0.f;
                        if (fx <= fy && fx <= fz) ex = 1.f; else if (fy <= fz) ey = 1.f; else ez = 1.f;
                        u1x = u0y*ez - u0z*ey; u1y = u0z*ex - u0x*ez; u1z = u0x*ey - u0y*ex;
                        n1 = sqrtf(u1x*u1x + u1y*u1y + u1z*u1z);
                    }
                    float in1 = 1.f/n1; u1x*=in1; u1y*=in1; u1z*=in1;
                    float u2x = u0y*u1z - u0z*u1y;
                    float u2y = u0z*u1x - u0x*u1z;
                    float u2z = u0x*u1y - u0y*u1x;
                    float detV = v00*(v11*v22 - v12*v21) - v01*(v10*v22 - v12*v20) + v02*(v10*v21 - v11*v20);
                    float dsg = (detV >= 0.f) ? 1.f : -1.f;
                    Rd00 = v00*u0x + v01*u1x + dsg*v02*u2x;
                    Rd01 = v00*u0y + v01*u1y + dsg*v02*u2y;
                    Rd02 = v00*u0z + v01*u1z + dsg*v02*u2z;
                    Rd10 = v10*u0x + v11*u1x + dsg*v12*u2x;
                    Rd11 = v10*u0y + v11*u1y + dsg*v12*u2y;
                    Rd12 = v10*u0z + v11*u1z + dsg*v12*u2z;
                    Rd20 = v20*u0x + v21*u1x + dsg*v22*u2x;
                    Rd21 = v20*u0y + v21*u1y + dsg*v22*u2y;
                    Rd22 = v20*u0z + v21*u1z + dsg*v22*u2z;
                }
            }
            float csx = ax*inv, csy = ay*inv, csz = az*inv;
            float ctx = bx*inv, cty = by*inv, ctz = bz*inv;
            float tdx = ctx - (Rd00*csx + Rd01*csy + Rd02*csz);
            float tdy = cty - (Rd10*csx + Rd11*csy + Rd12*csz);
            float tdz = ctz - (Rd20*csx + Rd21*csy + Rd22*csz);

            // T_new = delta * T_old
            float nr00 = Rd00*r00 + Rd01*r10 + Rd02*r20;
            float nr01 = Rd00*r01 + Rd01*r11 + Rd02*r21;
            float nr02 = Rd00*r02 + Rd01*r12 + Rd02*r22;
            float nr10 = Rd10*r00 + Rd11*r10 + Rd12*r20;
            float nr11 = Rd10*r01 + Rd11*r11 + Rd12*r21;
            float nr12 = Rd10*r02 + Rd11*r12 + Rd12*r22;
            float nr20 = Rd20*r00 + Rd21*r10 + Rd22*r20;
            float nr21 = Rd20*r01 + Rd21*r11 + Rd22*r21;
            float nr22 = Rd20*r02 + Rd21*r12 + Rd22*r22;
            float nt0 = Rd00*t0 + Rd01*t1 + Rd02*t2 + tdx;
            float nt1 = Rd10*t0 + Rd11*t1 + Rd12*t2 + tdy;
            float nt2 = Rd20*t0 + Rd21*t1 + Rd22*t2 + tdz;

            if (tid == 0) {
                bcastT4[0] = make_float4(nr00, nr01, nr02, nt0);
                bcastT4[1] = make_float4(nr10, nr11, nr12, nt1);
                bcastT4[2] = make_float4(nr20, nr21, nr22, nt2);
            }
        }
        __syncthreads();
        {
            float4 tA = bcastT4[0], tB = bcastT4[1], tC = bcastT4[2];
            r00=tA.x; r01=tA.y; r02=tA.z; t0=tA.w;
            r10=tB.x; r11=tB.y; r12=tB.z; t1=tB.w;
            r20=tC.x; r21=tC.y; r22=tC.z; t2=tC.w;
        }
    }

    if (chunk == 0 && tid == 0) {
        float* o = out + (size_t)b * 16;
        o[0]=r00;  o[1]=r01;  o[2]=r02;  o[3]=t0;
        o[4]=r10;  o[5]=r11;  o[6]=r12;  o[7]=t1;
        o[8]=r20;  o[9]=r21;  o[10]=r22; o[11]=t2;
        o[12]=0.f; o[13]=0.f; o[14]=0.f; o[15]=1.f;
    }
}

extern "C" void kernel_launch(void* const* d_in, const int* in_sizes, int n_in,
                              void* d_out, int out_size, void* d_ws, size_t ws_size,
                              hipStream_t stream) {
    const float* src = (const float*)d_in[0];
    const float* tgt = (const float*)d_in[1];
    float* out = (float*)d_out;
    float* ws  = (float*)d_ws;

    // zero the versioned slot region (64 KB) every launch — kills cross-replay aliasing
    hipMemsetAsync(d_ws, 0, 2 * BATCH * CHUNKS * 16 * sizeof(unsigned long long), stream);

    void* args[] = { (void*)&src, (void*)&tgt, (void*)&out, (void*)&ws };
    hipLaunchCooperativeKernel((const void*)icp_kernel,
                               dim3(BATCH * CHUNKS), dim3(NTHREADS),
                               args, 0, stream);
}